// Round 3
// baseline (402.867 us; speedup 1.0000x reference)
//
#include <hip/hip_runtime.h>
#include <hip/hip_bf16.h>

// CrossAttentionFusion: B=4, C=Cs=256, CI=128, H=W=64 -> N=M=4096
// R3: K and V stored in MFMA-fragment order so every attn main-loop global
// load is base+lane*16 (fully coalesced 1KB). Attn loop identical to R2
// (barrier-free, fixed-anchor softmax, in-register P relayout).
//
// K frag layout (QK A-operand, 32x32x16): element (b, key, ch) at
//   (b*128 + key>>5)*4096 + (ch>>4)*512 + ((ch>>3)&1)*256 + (key&31)*8 + (ch&7)
// V frag layout (PV B-operand): element (b, key, ch) at
//   (b*128 + key>>5)*8192 + (ch>>5)*1024 + ((key>>4)&1)*512
//                         + ((key>>3)&1)*256 + (ch&31)*8 + (key&7)

typedef __bf16  bf16x8  __attribute__((ext_vector_type(8)));
typedef float   f32x16  __attribute__((ext_vector_type(16)));

#define LOG2E 1.4426950408889634f

// ---------------------------------------------------------------------------
// Fused projections.
// ---------------------------------------------------------------------------
union ProjSmem {
  struct { float lx[16][64]; float lw[128][17]; } qk;
  struct { float lx[16][64]; float lw[256][17]; } v;
  __hip_bfloat16 t[256][72];   // [ch][key] staging; pitch 72 -> 144B rows (16B-aligned)
};

// Q: out[b][n][128] = bf16((W X + b) * scale)         (kfrag == false)
// K: fragment layout above                             (kfrag == true)
__device__ inline void proj_qk_body(
    const float* __restrict__ X, const float* __restrict__ W,
    const float* __restrict__ bias, __hip_bfloat16* __restrict__ oq,
    float scale, int idx, bool kfrag, ProjSmem& sm)
{
  const int b  = idx >> 6;
  const int n0 = (idx & 63) * 64;
  const int tid = threadIdx.x;
  const int o  = tid & 63;
  const int wv = tid >> 6;

  float acc[2][16];
#pragma unroll
  for (int g = 0; g < 2; g++)
#pragma unroll
    for (int k = 0; k < 16; k++) acc[g][k] = 0.f;

  const size_t xb = (size_t)b * 256 * 4096;
  for (int c0 = 0; c0 < 256; c0 += 16) {
#pragma unroll
    for (int i = 0; i < 4; i++) {
      int ii = i * 256 + tid; int cc = ii >> 6, nn = ii & 63;
      sm.qk.lx[cc][nn] = X[xb + (size_t)(c0 + cc) * 4096 + n0 + nn];
    }
#pragma unroll
    for (int i = 0; i < 8; i++) {
      int ii = i * 256 + tid; int oo = ii >> 4, cc = ii & 15;
      sm.qk.lw[oo][cc] = W[oo * 256 + c0 + cc];
    }
    __syncthreads();
#pragma unroll
    for (int cc = 0; cc < 16; cc++) {
      float w0 = sm.qk.lw[o][cc], w1 = sm.qk.lw[o + 64][cc];
      const float4* xp = (const float4*)&sm.qk.lx[cc][wv * 16];
#pragma unroll
      for (int k4 = 0; k4 < 4; k4++) {
        float4 xv = xp[k4];
        float xs[4] = {xv.x, xv.y, xv.z, xv.w};
#pragma unroll
        for (int k = 0; k < 4; k++) {
          acc[0][k4 * 4 + k] += w0 * xs[k];
          acc[1][k4 * 4 + k] += w1 * xs[k];
        }
      }
    }
    __syncthreads();
  }

  float bb[2] = {bias[o], bias[o + 64]};
#pragma unroll
  for (int g = 0; g < 2; g++)
#pragma unroll
    for (int k = 0; k < 16; k++) {
      float val = (acc[g][k] + bb[g]) * scale;
      int key = n0 + wv * 16 + k;
      int ch  = g * 64 + o;
      size_t ix;
      if (kfrag) {
        ix = ((size_t)(b * 128 + (key >> 5))) * 4096
           + (size_t)((ch >> 4) * 512 + ((ch >> 3) & 1) * 256
                      + (key & 31) * 8 + (ch & 7));
      } else {
        ix = ((size_t)(b * 4096 + key)) * 128 + ch;
      }
      oq[ix] = __float2bfloat16(val);
    }
}

// V: compute (lanes->ch), LDS transpose to [ch][key], write fragment layout.
__device__ inline void proj_v_body(
    const float* __restrict__ X, const float* __restrict__ W,
    const float* __restrict__ bias, __hip_bfloat16* __restrict__ outv,
    int idx, ProjSmem& sm)
{
  const int b  = idx >> 6;
  const int n0 = (idx & 63) * 64;
  const int tid = threadIdx.x;
  const int o  = tid & 63;
  const int wv = tid >> 6;

  float acc[4][16];
#pragma unroll
  for (int g = 0; g < 4; g++)
#pragma unroll
    for (int k = 0; k < 16; k++) acc[g][k] = 0.f;

  const size_t xb = (size_t)b * 256 * 4096;
  for (int c0 = 0; c0 < 256; c0 += 16) {
#pragma unroll
    for (int i = 0; i < 4; i++) {
      int ii = i * 256 + tid; int cc = ii >> 6, nn = ii & 63;
      sm.v.lx[cc][nn] = X[xb + (size_t)(c0 + cc) * 4096 + n0 + nn];
    }
#pragma unroll
    for (int i = 0; i < 16; i++) {
      int ii = i * 256 + tid; int oo = ii >> 4, cc = ii & 15;
      sm.v.lw[oo][cc] = W[oo * 256 + c0 + cc];
    }
    __syncthreads();
#pragma unroll
    for (int cc = 0; cc < 16; cc++) {
      float w[4] = {sm.v.lw[o][cc], sm.v.lw[o + 64][cc],
                    sm.v.lw[o + 128][cc], sm.v.lw[o + 192][cc]};
      const float4* xp = (const float4*)&sm.v.lx[cc][wv * 16];
#pragma unroll
      for (int k4 = 0; k4 < 4; k4++) {
        float4 xv = xp[k4];
        float xs[4] = {xv.x, xv.y, xv.z, xv.w};
#pragma unroll
        for (int k = 0; k < 4; k++)
#pragma unroll
          for (int g = 0; g < 4; g++)
            acc[g][k4 * 4 + k] += w[g] * xs[k];
      }
    }
    __syncthreads();
  }

  // stage t[ch][key_local]
#pragma unroll
  for (int g = 0; g < 4; g++) {
    float bb = bias[g * 64 + o];
#pragma unroll
    for (int k = 0; k < 16; k++)
      sm.t[g * 64 + o][wv * 16 + k] = __float2bfloat16(acc[g][k] + bb);
  }
  __syncthreads();

  // fragment-layout write: 2048 16B-chunks, tid-contiguous -> coalesced
  const size_t vbase = ((size_t)(b * 128 + (n0 >> 5))) * 8192;
#pragma unroll
  for (int r = 0; r < 8; r++) {
    int ix   = r * 256 + tid;          // 0..2047
    int lane = ix & 63;
    int ks   = (ix >> 6) & 1;
    int cht  = (ix >> 7) & 7;
    int kbl  = ix >> 10;
    int ch   = cht * 32 + (lane & 31);
    int keyl = kbl * 32 + ks * 16 + (lane >> 5) * 8;
    bf16x8 val = *(const bf16x8*)&sm.t[ch][keyl];
    *(bf16x8*)(outv + vbase + (size_t)ix * 8) = val;
  }
}

__global__ __launch_bounds__(256, 3) void proj_fused(
    const float* __restrict__ x, const float* __restrict__ z,
    const float* __restrict__ Wq, const float* __restrict__ bq,
    const float* __restrict__ Wk, const float* __restrict__ bk,
    const float* __restrict__ Wv, const float* __restrict__ bv,
    __hip_bfloat16* __restrict__ qp, __hip_bfloat16* __restrict__ kp,
    __hip_bfloat16* __restrict__ vp)
{
  __shared__ ProjSmem sm;
  const int bi = blockIdx.x;
  if (bi < 256)       proj_qk_body(x, Wq, bq, qp, LOG2E, bi, false, sm);
  else if (bi < 512)  proj_qk_body(z, Wk, bk, kp, 1.0f, bi - 256, true, sm);
  else                proj_v_body (z, Wv, bv, vp, bi - 512, sm);
}

// ---------------------------------------------------------------------------
// Flash attention, barrier-free main loop, fully-coalesced fragment loads.
// Block: (batch b, 32 queries). Wave wv: private keys [wv*1024, wv*1024+1024).
// ---------------------------------------------------------------------------
struct AttnSmem {
  float ostage[256][33];   // [ch][q] fp32 merge/transpose, pad 33
  float redu[4][32];       // iter-0 anchor exchange; reused for l partials
};

union U4 { unsigned u[4]; bf16x8 v; };

__global__ __launch_bounds__(256, 2) void attn_kernel(
    const __hip_bfloat16* __restrict__ qv, const __hip_bfloat16* __restrict__ kv,
    const __hip_bfloat16* __restrict__ vv,
    const float* __restrict__ x_main, const float* __restrict__ gammap,
    float* __restrict__ out)
{
  __shared__ AttnSmem sm;
  const int i  = blockIdx.x;
  // XCD-stable: blockIdx%8 -> XCD; pin each XCD-pair to one batch so that
  // batch's K+V (~3MB) stays L2-resident.
  const int b  = (i & 7) >> 1;
  const int nt = ((i >> 3) << 1) | (i & 1);
  const int n0 = nt * 32;
  const int tid  = threadIdx.x;
  const int wv   = tid >> 6, lane = tid & 63, l32 = lane & 31, half = lane >> 5;

  // Q B-fragments: lane holds q[n0+l32][cs*16 + half*8 + j] (one-time, scattered ok)
  bf16x8 qf[8];
  {
    const __hip_bfloat16* qb = qv + ((size_t)(b * 4096 + n0 + l32)) * 128 + half * 8;
#pragma unroll
    for (int cs = 0; cs < 8; cs++) qf[cs] = *(const bf16x8*)(qb + cs * 16);
  }

  // fragment-layout bases for this wave's private 1024-key range
  const __hip_bfloat16* kbase = kv + ((size_t)(b * 128 + wv * 32)) * 4096 + lane * 8;
  const __hip_bfloat16* vbase = vv + ((size_t)(b * 128 + wv * 32)) * 8192 + lane * 8;

  f32x16 Oacc[8];
#pragma unroll
  for (int t = 0; t < 8; t++)
#pragma unroll
    for (int r = 0; r < 16; r++) Oacc[t][r] = 0.f;

  float m0 = 0.f;
  float l_lane = 0.f;

  // S^T tile for 32 keys: A=K (frag loads, coalesced), B=Q.
  auto qk_tile = [&](int it) -> f32x16 {
    f32x16 S;
#pragma unroll
    for (int r = 0; r < 16; r++) S[r] = 0.f;
    const __hip_bfloat16* kp = kbase + (size_t)it * 4096;
#pragma unroll
    for (int cs = 0; cs < 8; cs++) {
      bf16x8 kf = *(const bf16x8*)(kp + cs * 512);
      S = __builtin_amdgcn_mfma_f32_32x32x16_bf16(kf, qf[cs], S, 0, 0, 0);
    }
    return S;
  };

  // P = exp2(S - m0); A-layout P frags in-register; PV MFMAs (coalesced V).
  auto pv_tile = [&](int it, const f32x16& S) {
    unsigned p2[8];
    float lsub = 0.f;
#pragma unroll
    for (int t = 0; t < 8; t++) {
      float a = exp2f(S[2 * t]     - m0);
      float c = exp2f(S[2 * t + 1] - m0);
      lsub += a + c;
      union { __hip_bfloat162 h; unsigned u; } cv;
      cv.h = __float22bfloat162_rn(float2{a, c});
      p2[t] = cv.u;
    }
    l_lane += lsub;
    unsigned r2[8];
#pragma unroll
    for (int t = 0; t < 8; t++) r2[t] = (unsigned)__shfl_xor((int)p2[t], 32);
    U4 f0, f1;
    if (half == 0) {
      f0.u[0] = p2[0]; f0.u[1] = p2[1]; f0.u[2] = r2[0]; f0.u[3] = r2[1];
      f1.u[0] = p2[4]; f1.u[1] = p2[5]; f1.u[2] = r2[4]; f1.u[3] = r2[5];
    } else {
      f0.u[0] = r2[2]; f0.u[1] = r2[3]; f0.u[2] = p2[2]; f0.u[3] = p2[3];
      f1.u[0] = r2[6]; f1.u[1] = r2[7]; f1.u[2] = p2[6]; f1.u[3] = p2[7];
    }
    const bf16x8 pf0 = f0.v, pf1 = f1.v;
    const __hip_bfloat16* vp0 = vbase + (size_t)it * 8192;
#pragma unroll
    for (int cht = 0; cht < 8; cht++) {
      bf16x8 v0 = *(const bf16x8*)(vp0 + cht * 1024);
      Oacc[cht] = __builtin_amdgcn_mfma_f32_32x32x16_bf16(pf0, v0, Oacc[cht], 0, 0, 0);
      bf16x8 v1 = *(const bf16x8*)(vp0 + cht * 1024 + 512);
      Oacc[cht] = __builtin_amdgcn_mfma_f32_32x32x16_bf16(pf1, v1, Oacc[cht], 0, 0, 0);
    }
  };

  // ---- iter 0 (peeled): anchor m0 = max over first 128 keys ----
  {
    f32x16 S = qk_tile(0);
    float mh = S[0];
#pragma unroll
    for (int r = 1; r < 16; r++) mh = fmaxf(mh, S[r]);
    mh = fmaxf(mh, __shfl_xor(mh, 32));
    if (lane < 32) sm.redu[wv][l32] = mh;
    __syncthreads();
    m0 = fmaxf(fmaxf(sm.redu[0][l32], sm.redu[1][l32]),
               fmaxf(sm.redu[2][l32], sm.redu[3][l32]));
    pv_tile(0, S);
  }

  // ---- barrier-free main loop ----
#pragma unroll 1
  for (int it = 1; it < 32; ++it) {
    f32x16 S = qk_tile(it);
    pv_tile(it, S);
  }

  // ---- epilogue: merge 4 waves' O via rotated-quarter LDS accumulation ----
  __syncthreads();
  float lfull = l_lane + __shfl_xor(l_lane, 32);
  if (lane < 32) sm.redu[wv][l32] = lfull;
#pragma unroll
  for (int p = 0; p < 4; ++p) {
    const int qt = (wv + p) & 3;
#pragma unroll
    for (int cq = 0; cq < 2; ++cq) {
      const int cht = qt * 2 + cq;
#pragma unroll
      for (int r = 0; r < 16; ++r) {
        const int row = (r & 3) + 8 * (r >> 2) + 4 * half;
        if (p == 0) sm.ostage[cht * 32 + l32][row]  = Oacc[cht][r];
        else        sm.ostage[cht * 32 + l32][row] += Oacc[cht][r];
      }
    }
    __syncthreads();
  }

  const float gmm = gammap[0];
  const int nr = tid & 31;
  const int og = tid >> 5;
  const float ltot = sm.redu[0][nr] + sm.redu[1][nr] + sm.redu[2][nr] + sm.redu[3][nr];
  const float rinv = 1.0f / ltot;
#pragma unroll
  for (int j = 0; j < 32; ++j) {
    int oo = og * 32 + j;
    size_t g = ((size_t)(b * 256 + oo)) * 4096 + n0 + nr;
    out[g] = gmm * sm.ostage[oo][nr] * rinv + x_main[g];
  }
}

// ---------------------------------------------------------------------------
extern "C" void kernel_launch(void* const* d_in, const int* in_sizes, int n_in,
                              void* d_out, int out_size, void* d_ws, size_t ws_size,
                              hipStream_t stream) {
  (void)in_sizes; (void)n_in; (void)out_size; (void)ws_size;
  const float* x  = (const float*)d_in[0];
  const float* z  = (const float*)d_in[1];
  const float* Wq = (const float*)d_in[2];
  const float* bq = (const float*)d_in[3];
  const float* Wk = (const float*)d_in[4];
  const float* bk = (const float*)d_in[5];
  const float* Wv = (const float*)d_in[6];
  const float* bv = (const float*)d_in[7];
  const float* gm = (const float*)d_in[8];
  float* out = (float*)d_out;

  char* ws = (char*)d_ws;
  const size_t QSZ = (size_t)4 * 4096 * 128 * sizeof(__hip_bfloat16);  // 4 MiB
  __hip_bfloat16* qp = (__hip_bfloat16*)(ws);
  __hip_bfloat16* kp = (__hip_bfloat16*)(ws + QSZ);
  __hip_bfloat16* vp = (__hip_bfloat16*)(ws + 2 * QSZ);                // 8 MiB

  proj_fused<<<768, 256, 0, stream>>>(x, z, Wq, bq, Wk, bk, Wv, bv, qp, kp, vp);
  attn_kernel<<<512, 256, 0, stream>>>(qp, kp, vp, x, gm, out);
}

// Round 4
// 285.237 us; speedup vs baseline: 1.4124x; 1.4124x over previous
//
#include <hip/hip_runtime.h>
#include <hip/hip_bf16.h>

// CrossAttentionFusion: B=4, C=Cs=256, CI=128, H=W=64 -> N=M=4096
// R4: attn rewritten around global_load_lds DMA + LDS double-buffering.
//  - 256 blocks x 512 thr: block = (batch, 64 queries); 8 waves (qh,kh,chh).
//  - 64 keys/iter staged to LDS by DMA (48 KiB/tile, 2 buffers = 96 KiB).
//    One __syncthreads per iter; its implicit vmcnt(0) waits only on the
//    tile issued a full iteration ago (next tile's DMA issued after).
//  - Wave computes 32x32 S^T tile (A=K,B=Q), in-register softmax + P
//    relayout (R2 trick), partial O[32q][128ch] over its 32-key half;
//    kh halves merged in epilogue. Oacc[4]=64 AGPR -> pressure solved.
//  - proj_fused unchanged from R3 (global K/V frag layouts identical).

typedef __bf16  bf16x8  __attribute__((ext_vector_type(8)));
typedef float   f32x16  __attribute__((ext_vector_type(16)));

#define LOG2E 1.4426950408889634f

// ---------------------------------------------------------------------------
// Fused projections (unchanged from R3).
// ---------------------------------------------------------------------------
union ProjSmem {
  struct { float lx[16][64]; float lw[128][17]; } qk;
  struct { float lx[16][64]; float lw[256][17]; } v;
  __hip_bfloat16 t[256][72];
};

__device__ inline void proj_qk_body(
    const float* __restrict__ X, const float* __restrict__ W,
    const float* __restrict__ bias, __hip_bfloat16* __restrict__ oq,
    float scale, int idx, bool kfrag, ProjSmem& sm)
{
  const int b  = idx >> 6;
  const int n0 = (idx & 63) * 64;
  const int tid = threadIdx.x;
  const int o  = tid & 63;
  const int wv = tid >> 6;

  float acc[2][16];
#pragma unroll
  for (int g = 0; g < 2; g++)
#pragma unroll
    for (int k = 0; k < 16; k++) acc[g][k] = 0.f;

  const size_t xb = (size_t)b * 256 * 4096;
  for (int c0 = 0; c0 < 256; c0 += 16) {
#pragma unroll
    for (int i = 0; i < 4; i++) {
      int ii = i * 256 + tid; int cc = ii >> 6, nn = ii & 63;
      sm.qk.lx[cc][nn] = X[xb + (size_t)(c0 + cc) * 4096 + n0 + nn];
    }
#pragma unroll
    for (int i = 0; i < 8; i++) {
      int ii = i * 256 + tid; int oo = ii >> 4, cc = ii & 15;
      sm.qk.lw[oo][cc] = W[oo * 256 + c0 + cc];
    }
    __syncthreads();
#pragma unroll
    for (int cc = 0; cc < 16; cc++) {
      float w0 = sm.qk.lw[o][cc], w1 = sm.qk.lw[o + 64][cc];
      const float4* xp = (const float4*)&sm.qk.lx[cc][wv * 16];
#pragma unroll
      for (int k4 = 0; k4 < 4; k4++) {
        float4 xv = xp[k4];
        float xs[4] = {xv.x, xv.y, xv.z, xv.w};
#pragma unroll
        for (int k = 0; k < 4; k++) {
          acc[0][k4 * 4 + k] += w0 * xs[k];
          acc[1][k4 * 4 + k] += w1 * xs[k];
        }
      }
    }
    __syncthreads();
  }

  float bb[2] = {bias[o], bias[o + 64]};
#pragma unroll
  for (int g = 0; g < 2; g++)
#pragma unroll
    for (int k = 0; k < 16; k++) {
      float val = (acc[g][k] + bb[g]) * scale;
      int key = n0 + wv * 16 + k;
      int ch  = g * 64 + o;
      size_t ix;
      if (kfrag) {
        ix = ((size_t)(b * 128 + (key >> 5))) * 4096
           + (size_t)((ch >> 4) * 512 + ((ch >> 3) & 1) * 256
                      + (key & 31) * 8 + (ch & 7));
      } else {
        ix = ((size_t)(b * 4096 + key)) * 128 + ch;
      }
      oq[ix] = __float2bfloat16(val);
    }
}

__device__ inline void proj_v_body(
    const float* __restrict__ X, const float* __restrict__ W,
    const float* __restrict__ bias, __hip_bfloat16* __restrict__ outv,
    int idx, ProjSmem& sm)
{
  const int b  = idx >> 6;
  const int n0 = (idx & 63) * 64;
  const int tid = threadIdx.x;
  const int o  = tid & 63;
  const int wv = tid >> 6;

  float acc[4][16];
#pragma unroll
  for (int g = 0; g < 4; g++)
#pragma unroll
    for (int k = 0; k < 16; k++) acc[g][k] = 0.f;

  const size_t xb = (size_t)b * 256 * 4096;
  for (int c0 = 0; c0 < 256; c0 += 16) {
#pragma unroll
    for (int i = 0; i < 4; i++) {
      int ii = i * 256 + tid; int cc = ii >> 6, nn = ii & 63;
      sm.v.lx[cc][nn] = X[xb + (size_t)(c0 + cc) * 4096 + n0 + nn];
    }
#pragma unroll
    for (int i = 0; i < 16; i++) {
      int ii = i * 256 + tid; int oo = ii >> 4, cc = ii & 15;
      sm.v.lw[oo][cc] = W[oo * 256 + c0 + cc];
    }
    __syncthreads();
#pragma unroll
    for (int cc = 0; cc < 16; cc++) {
      float w[4] = {sm.v.lw[o][cc], sm.v.lw[o + 64][cc],
                    sm.v.lw[o + 128][cc], sm.v.lw[o + 192][cc]};
      const float4* xp = (const float4*)&sm.v.lx[cc][wv * 16];
#pragma unroll
      for (int k4 = 0; k4 < 4; k4++) {
        float4 xv = xp[k4];
        float xs[4] = {xv.x, xv.y, xv.z, xv.w};
#pragma unroll
        for (int k = 0; k < 4; k++)
#pragma unroll
          for (int g = 0; g < 4; g++)
            acc[g][k4 * 4 + k] += w[g] * xs[k];
      }
    }
    __syncthreads();
  }

#pragma unroll
  for (int g = 0; g < 4; g++) {
    float bb = bias[g * 64 + o];
#pragma unroll
    for (int k = 0; k < 16; k++)
      sm.t[g * 64 + o][wv * 16 + k] = __float2bfloat16(acc[g][k] + bb);
  }
  __syncthreads();

  const size_t vbase = ((size_t)(b * 128 + (n0 >> 5))) * 8192;
#pragma unroll
  for (int r = 0; r < 8; r++) {
    int ix   = r * 256 + tid;
    int lane = ix & 63;
    int ks   = (ix >> 6) & 1;
    int cht  = (ix >> 7) & 7;
    int kbl  = ix >> 10;
    int ch   = cht * 32 + (lane & 31);
    int keyl = kbl * 32 + ks * 16 + (lane >> 5) * 8;
    bf16x8 val = *(const bf16x8*)&sm.t[ch][keyl];
    *(bf16x8*)(outv + vbase + (size_t)ix * 8) = val;
  }
}

__global__ __launch_bounds__(256, 3) void proj_fused(
    const float* __restrict__ x, const float* __restrict__ z,
    const float* __restrict__ Wq, const float* __restrict__ bq,
    const float* __restrict__ Wk, const float* __restrict__ bk,
    const float* __restrict__ Wv, const float* __restrict__ bv,
    __hip_bfloat16* __restrict__ qp, __hip_bfloat16* __restrict__ kp,
    __hip_bfloat16* __restrict__ vp)
{
  __shared__ ProjSmem sm;
  const int bi = blockIdx.x;
  if (bi < 256)       proj_qk_body(x, Wq, bq, qp, LOG2E, bi, false, sm);
  else if (bi < 512)  proj_qk_body(z, Wk, bk, kp, 1.0f, bi - 256, true, sm);
  else                proj_v_body (z, Wv, bv, vp, bi - 512, sm);
}

// ---------------------------------------------------------------------------
// Flash attention with DMA-staged LDS double buffering.
// ---------------------------------------------------------------------------
struct AttnSmem {
  union {
    struct {
      __hip_bfloat16 kbuf[2][8192];    // 2 x 16 KiB (64 keys x 128 ch, frag order)
      __hip_bfloat16 vbuf[2][16384];   // 2 x 32 KiB (64 keys x 256 ch, frag order)
    } p;
    float ostage[256][65];             // [ch][q] merge/transpose, pitch 65
  } u;
  float redu[8][32];                   // anchor exchange, then l partials
  float rinv[64];
};

union U4 { unsigned u[4]; bf16x8 v; };

__device__ inline void dma16(const __hip_bfloat16* g, __hip_bfloat16* l) {
  __builtin_amdgcn_global_load_lds(
      (const __attribute__((address_space(1))) unsigned int*)g,
      (__attribute__((address_space(3))) unsigned int*)l, 16, 0, 0);
}

__global__ __launch_bounds__(512, 2) void attn_kernel(
    const __hip_bfloat16* __restrict__ qv, const __hip_bfloat16* __restrict__ kv,
    const __hip_bfloat16* __restrict__ vv,
    const float* __restrict__ x_main, const float* __restrict__ gammap,
    float* __restrict__ out)
{
  extern __shared__ char dynsmem[];
  AttnSmem& sm = *reinterpret_cast<AttnSmem*>(dynsmem);

  const int i  = blockIdx.x;
  // XCD-stable: blockIdx%8 -> XCD; pin each XCD-pair to one batch.
  const int b  = (i & 7) >> 1;
  const int qt = ((i >> 3) << 1) | (i & 1);
  const int n0 = qt * 64;
  const int tid  = threadIdx.x;
  const int w    = tid >> 6, lane = tid & 63, l32 = lane & 31, half = lane >> 5;
  const int qh   = w >> 2, kh = (w >> 1) & 1, chh = w & 1;

  // Q B-fragments for this wave's 32 queries (one-time scattered global load)
  bf16x8 qf[8];
  {
    const __hip_bfloat16* qb =
        qv + ((size_t)(b * 4096 + n0 + qh * 32 + l32)) * 128 + half * 8;
#pragma unroll
    for (int cs = 0; cs < 8; cs++) qf[cs] = *(const bf16x8*)(qb + cs * 16);
  }

  const __hip_bfloat16* kg = kv + (size_t)(b * 128) * 4096;  // + t*8192 per tile
  const __hip_bfloat16* vg = vv + (size_t)(b * 128) * 8192;  // + t*16384 per tile

  // DMA one 64-key tile (K 16 KiB + V 32 KiB = 48 chunks of 1 KiB); wave w
  // stages chunks [w*6, w*6+6). LDS dest = chunk base + lane*16 (HW pattern).
  auto stage = [&](int t) {
    __hip_bfloat16* kd = sm.u.p.kbuf[t & 1];
    __hip_bfloat16* vd = sm.u.p.vbuf[t & 1];
    const __hip_bfloat16* ksrc = kg + (size_t)t * 8192  + lane * 8;
    const __hip_bfloat16* vsrc = vg + (size_t)t * 16384 + lane * 8;
#pragma unroll
    for (int c = 0; c < 6; c++) {
      int ck = w * 6 + c;
      if (ck < 16) dma16(ksrc + ck * 512,        kd + ck * 512        + lane * 8);
      else         dma16(vsrc + (ck - 16) * 512, vd + (ck - 16) * 512 + lane * 8);
    }
  };

  f32x16 Oacc[4];
#pragma unroll
  for (int c = 0; c < 4; c++)
#pragma unroll
    for (int r = 0; r < 16; r++) Oacc[c][r] = 0.f;

  float m0 = 0.f;
  float l_lane = 0.f;

  // S^T (32 keys of kh-half x 32 queries) from LDS K frags; two independent
  // 4-chains to halve MFMA dependency depth.
  auto qk_tile = [&](int t) -> f32x16 {
    const __hip_bfloat16* kbase = sm.u.p.kbuf[t & 1] + kh * 4096 + lane * 8;
    f32x16 Sa, Sb;
#pragma unroll
    for (int r = 0; r < 16; r++) { Sa[r] = 0.f; Sb[r] = 0.f; }
#pragma unroll
    for (int cs = 0; cs < 4; cs++) {
      bf16x8 kf = *(const bf16x8*)(kbase + cs * 512);
      Sa = __builtin_amdgcn_mfma_f32_32x32x16_bf16(kf, qf[cs], Sa, 0, 0, 0);
    }
#pragma unroll
    for (int cs = 4; cs < 8; cs++) {
      bf16x8 kf = *(const bf16x8*)(kbase + cs * 512);
      Sb = __builtin_amdgcn_mfma_f32_32x32x16_bf16(kf, qf[cs], Sb, 0, 0, 0);
    }
    return Sa + Sb;
  };

  // P = exp2(S - m0) -> in-register A-layout frags -> PV over 128 ch (chh half)
  auto pv_tile = [&](int t, const f32x16& S) {
    unsigned p2[8];
    float lsub = 0.f;
#pragma unroll
    for (int t2 = 0; t2 < 8; t2++) {
      float a = exp2f(S[2 * t2]     - m0);
      float c = exp2f(S[2 * t2 + 1] - m0);
      lsub += a + c;
      union { __hip_bfloat162 h; unsigned u; } cv;
      cv.h = __float22bfloat162_rn(float2{a, c});
      p2[t2] = cv.u;
    }
    l_lane += lsub;
    unsigned r2[8];
#pragma unroll
    for (int t2 = 0; t2 < 8; t2++) r2[t2] = (unsigned)__shfl_xor((int)p2[t2], 32);
    U4 f0, f1;
    if (half == 0) {
      f0.u[0] = p2[0]; f0.u[1] = p2[1]; f0.u[2] = r2[0]; f0.u[3] = r2[1];
      f1.u[0] = p2[4]; f1.u[1] = p2[5]; f1.u[2] = r2[4]; f1.u[3] = r2[5];
    } else {
      f0.u[0] = r2[2]; f0.u[1] = r2[3]; f0.u[2] = p2[2]; f0.u[3] = p2[3];
      f1.u[0] = r2[6]; f1.u[1] = r2[7]; f1.u[2] = p2[6]; f1.u[3] = p2[7];
    }
    const bf16x8 pf0 = f0.v, pf1 = f1.v;
    const __hip_bfloat16* vbase =
        sm.u.p.vbuf[t & 1] + kh * 8192 + chh * 4096 + lane * 8;
#pragma unroll
    for (int c = 0; c < 4; c++) {
      bf16x8 v0 = *(const bf16x8*)(vbase + c * 1024);
      Oacc[c] = __builtin_amdgcn_mfma_f32_32x32x16_bf16(pf0, v0, Oacc[c], 0, 0, 0);
      bf16x8 v1 = *(const bf16x8*)(vbase + c * 1024 + 512);
      Oacc[c] = __builtin_amdgcn_mfma_f32_32x32x16_bf16(pf1, v1, Oacc[c], 0, 0, 0);
    }
  };

  // ---- prologue + iter 0 (anchor) ----
  stage(0);
  __syncthreads();                       // vmcnt(0): tile 0 landed
  stage(1);
  {
    f32x16 S = qk_tile(0);
    float mh = S[0];
#pragma unroll
    for (int r = 1; r < 16; r++) mh = fmaxf(mh, S[r]);
    mh = fmaxf(mh, __shfl_xor(mh, 32));
    if (lane < 32) sm.redu[w][l32] = mh;
    __syncthreads();                     // one-time: also drains stage(1)
    m0 = fmaxf(fmaxf(sm.redu[qh * 4 + 0][l32], sm.redu[qh * 4 + 1][l32]),
               fmaxf(sm.redu[qh * 4 + 2][l32], sm.redu[qh * 4 + 3][l32]));
    pv_tile(0, S);
  }

  // ---- pipelined main loop: 1 barrier/iter ----
#pragma unroll 1
  for (int t = 1; t < 64; ++t) {
    __syncthreads();                     // vmcnt(0) waits tile t (issued iter t-1)
    if (t < 63) stage(t + 1);            // prefetch into buf (t+1)&1
    f32x16 S = qk_tile(t);
    pv_tile(t, S);
  }

  // ---- epilogue: publish l, merge kh halves via ostage, fused writeout ----
  float lfull = l_lane + __shfl_xor(l_lane, 32);
  if (lane < 32) sm.redu[w][l32] = lfull;
  __syncthreads();                       // E1: loop reads done; l published
  if (kh == 0) {
#pragma unroll
    for (int c = 0; c < 4; c++) {
      int ch = (chh * 4 + c) * 32 + l32;
#pragma unroll
      for (int r = 0; r < 16; r++) {
        int q = qh * 32 + (r & 3) + 8 * (r >> 2) + 4 * half;
        sm.u.ostage[ch][q] = Oacc[c][r];
      }
    }
  }
  if (tid < 64) {
    int qq = tid >> 5, ql = tid & 31;
    float lt = sm.redu[qq * 4 + 0][ql] + sm.redu[qq * 4 + 2][ql];
    sm.rinv[tid] = 1.0f / lt;
  }
  __syncthreads();                       // E2
  if (kh == 1) {
#pragma unroll
    for (int c = 0; c < 4; c++) {
      int ch = (chh * 4 + c) * 32 + l32;
#pragma unroll
      for (int r = 0; r < 16; r++) {
        int q = qh * 32 + (r & 3) + 8 * (r >> 2) + 4 * half;
        sm.u.ostage[ch][q] += Oacc[c][r];
      }
    }
  }
  __syncthreads();                       // E3

  const float gmm = gammap[0];
#pragma unroll
  for (int j = 0; j < 32; ++j) {
    int ch = w + 8 * j;
    size_t g = ((size_t)(b * 256 + ch)) * 4096 + n0 + lane;
    out[g] = gmm * sm.u.ostage[ch][lane] * sm.rinv[lane] + x_main[g];
  }
}

// ---------------------------------------------------------------------------
extern "C" void kernel_launch(void* const* d_in, const int* in_sizes, int n_in,
                              void* d_out, int out_size, void* d_ws, size_t ws_size,
                              hipStream_t stream) {
  (void)in_sizes; (void)n_in; (void)out_size; (void)ws_size;
  const float* x  = (const float*)d_in[0];
  const float* z  = (const float*)d_in[1];
  const float* Wq = (const float*)d_in[2];
  const float* bq = (const float*)d_in[3];
  const float* Wk = (const float*)d_in[4];
  const float* bk = (const float*)d_in[5];
  const float* Wv = (const float*)d_in[6];
  const float* bv = (const float*)d_in[7];
  const float* gm = (const float*)d_in[8];
  float* out = (float*)d_out;

  char* ws = (char*)d_ws;
  const size_t QSZ = (size_t)4 * 4096 * 128 * sizeof(__hip_bfloat16);  // 4 MiB
  __hip_bfloat16* qp = (__hip_bfloat16*)(ws);
  __hip_bfloat16* kp = (__hip_bfloat16*)(ws + QSZ);
  __hip_bfloat16* vp = (__hip_bfloat16*)(ws + 2 * QSZ);                // 8 MiB

  const int smem_bytes = (int)sizeof(AttnSmem);   // ~97.3 KiB < 160 KiB
  (void)hipFuncSetAttribute((const void*)attn_kernel,
                            hipFuncAttributeMaxDynamicSharedMemorySize,
                            smem_bytes);

  proj_fused<<<768, 256, 0, stream>>>(x, z, Wq, bq, Wk, bk, Wv, bv, qp, kp, vp);
  attn_kernel<<<256, 512, smem_bytes, stream>>>(qp, kp, vp, x, gm, out);
}

// Round 5
// 242.175 us; speedup vs baseline: 1.6635x; 1.1778x over previous
//
#include <hip/hip_runtime.h>
#include <hip/hip_bf16.h>

// CrossAttentionFusion: B=4, C=Cs=256, CI=128, H=W=64 -> N=M=4096
// R5:
//  - proj_mfma: projections on the matrix pipe. Per block: DMA-stage
//    X[256ch][64pix] fp32 to LDS, W as bf16 A-frags in VGPRs, 32 MFMAs/wave,
//    store directly in attn-consumable layouts (q row-major, K-frag, V-frag).
//  - attn: 512 blocks x 256 thr (32 q), waves=(kh,chh). K: DMA+LDS double
//    buffer (16 KiB/tile). V: direct global frag-layout loads (L2-resident).
//    Softmax: fixed 2^-64 rescale (no anchor pass, no online rescale).
//    LDS ~34 KiB, 2 blocks/CU -> decoupled barriers.
//
// K frag layout: (b,key,ch) at (b*128+key>>5)*4096 + (ch>>4)*512
//                 + ((ch>>3)&1)*256 + (key&31)*8 + (ch&7)
// V frag layout: (b,key,ch) at (b*128+key>>5)*8192 + (ch>>5)*1024
//                 + ((key>>4)&1)*512 + ((key>>3)&1)*256 + (ch&31)*8 + (key&7)

typedef __bf16  bf16x8  __attribute__((ext_vector_type(8)));
typedef float   f32x16  __attribute__((ext_vector_type(16)));

#define LOG2E 1.4426950408889634f

union BF8 { __hip_bfloat162 h[4]; bf16x8 v; };

__device__ inline bf16x8 pack8(const float f[8]) {
  BF8 u;
#pragma unroll
  for (int i = 0; i < 4; i++)
    u.h[i] = __float22bfloat162_rn(float2{f[2 * i], f[2 * i + 1]});
  return u.v;
}

__device__ inline void dma16(const void* g, void* l) {
  __builtin_amdgcn_global_load_lds(
      (const __attribute__((address_space(1))) unsigned int*)g,
      (__attribute__((address_space(3))) unsigned int*)l, 16, 0, 0);
}

// ---------------------------------------------------------------------------
// MFMA projections. Grid 1024: [0,256) q, [256,512) k, [512,1024) v.
// Block: (b, 64-pixel tile); 4 waves x 32 out-ch; K-dim = 256 input ch.
// ---------------------------------------------------------------------------
__global__ __launch_bounds__(256, 2) void proj_mfma(
    const float* __restrict__ x, const float* __restrict__ z,
    const float* __restrict__ Wq, const float* __restrict__ bq,
    const float* __restrict__ Wk, const float* __restrict__ bk,
    const float* __restrict__ Wv, const float* __restrict__ bv,
    __hip_bfloat16* __restrict__ qp, __hip_bfloat16* __restrict__ kp,
    __hip_bfloat16* __restrict__ vp)
{
  extern __shared__ float xs[];   // [256 ch][64 pix] fp32, rows contiguous
  const int bi = blockIdx.x;
  int mode, b, t, h = 0;
  if (bi < 512) { mode = bi >> 8; b = (bi & 255) >> 6; t = bi & 63; }
  else { int j = bi - 512; mode = 2; b = j >> 7; t = (j & 127) >> 1; h = j & 1; }
  const int n0 = t * 64;
  const float* X    = (mode == 0) ? x  : z;
  const float* W    = (mode == 0) ? Wq : (mode == 1) ? Wk : Wv;
  const float* bias = (mode == 0) ? bq : (mode == 1) ? bk : bv;

  const int tid = threadIdx.x;
  const int w = tid >> 6, lane = tid & 63, l32 = lane & 31, half = lane >> 5;

  // ---- DMA X tile: 16 instrs/wave, each stages 4 rows (1 KiB) ----
  {
    const float* gx = X + (size_t)b * (256 * 4096) + n0
                    + (size_t)(lane >> 4) * 4096 + (lane & 15) * 4;
#pragma unroll
    for (int it = 0; it < 16; it++) {
      int ch0 = w * 64 + it * 4;
      dma16(gx + (size_t)ch0 * 4096, xs + ch0 * 64 + lane * 4);
    }
  }

  // ---- W fragments: 16 x bf16x8 (64 VGPR), lane = out-ch l32 ----
  const int obase = (mode == 2) ? 128 * h : 0;
  const int och = obase + w * 32 + l32;
  bf16x8 wf[16];
  {
    const float* wr = W + (size_t)och * 256 + half * 8;
#pragma unroll
    for (int cs = 0; cs < 16; cs++) {
      float f[8];
#pragma unroll
      for (int j = 0; j < 8; j++) f[j] = wr[cs * 16 + j];
      wf[cs] = pack8(f);
    }
  }
  __syncthreads();   // X tile landed (vmcnt(0) incl. DMA)

  f32x16 O0, O1;
#pragma unroll
  for (int r = 0; r < 16; r++) { O0[r] = 0.f; O1[r] = 0.f; }

  // B/A X-frag reads: lane jj-loop strided 64 words -> conflict-free
  const float* xc = xs + (half * 8) * 64 + l32;
  if (mode != 2) {
    // q/k: D[pix-row][ch-col]  (A=X, B=W)
#pragma unroll
    for (int cs = 0; cs < 16; cs++) {
      float f0[8], f1[8];
#pragma unroll
      for (int j = 0; j < 8; j++) {
        f0[j] = xc[cs * 1024 + j * 64];
        f1[j] = xc[cs * 1024 + j * 64 + 32];
      }
      bf16x8 x0 = pack8(f0), x1 = pack8(f1);
      O0 = __builtin_amdgcn_mfma_f32_32x32x16_bf16(x0, wf[cs], O0, 0, 0, 0);
      O1 = __builtin_amdgcn_mfma_f32_32x32x16_bf16(x1, wf[cs], O1, 0, 0, 0);
    }
  } else {
    // v: D[ch-row][pix-col]  (A=W, B=X)
#pragma unroll
    for (int cs = 0; cs < 16; cs++) {
      float f0[8], f1[8];
#pragma unroll
      for (int j = 0; j < 8; j++) {
        f0[j] = xc[cs * 1024 + j * 64];
        f1[j] = xc[cs * 1024 + j * 64 + 32];
      }
      bf16x8 x0 = pack8(f0), x1 = pack8(f1);
      O0 = __builtin_amdgcn_mfma_f32_32x32x16_bf16(wf[cs], x0, O0, 0, 0, 0);
      O1 = __builtin_amdgcn_mfma_f32_32x32x16_bf16(wf[cs], x1, O1, 0, 0, 0);
    }
  }

  if (mode == 0) {
    // q row-major [b][n][128], log2e folded in
    const float bb = bias[och];
    __hip_bfloat16* qb = qp + (size_t)(b * 4096 + n0) * 128 + och;
#pragma unroll
    for (int p = 0; p < 2; p++) {
      const f32x16& O = p ? O1 : O0;
#pragma unroll
      for (int r = 0; r < 16; r++) {
        int pix = p * 32 + (r & 3) + 8 * (r >> 2) + 4 * half;
        qb[(size_t)pix * 128] = __float2bfloat16((O[r] + bb) * LOG2E);
      }
    }
  } else if (mode == 1) {
    // K-frag layout
    const float bb = bias[och];
    __hip_bfloat16* kb = kp + (size_t)(b * 128) * 4096
        + (och >> 4) * 512 + ((och >> 3) & 1) * 256 + (och & 7);
#pragma unroll
    for (int p = 0; p < 2; p++) {
      const f32x16& O = p ? O1 : O0;
#pragma unroll
      for (int r = 0; r < 16; r++) {
        int key = n0 + p * 32 + (r & 3) + 8 * (r >> 2) + 4 * half;
        kb[(size_t)(key >> 5) * 4096 + (key & 31) * 8] =
            __float2bfloat16(O[r] + bb);
      }
    }
  } else {
    // V-frag layout: lane = key-col, regs = ch-rows
    float bvv[16];
#pragma unroll
    for (int r = 0; r < 16; r++)
      bvv[r] = bias[128 * h + 32 * w + (r & 3) + 8 * (r >> 2) + 4 * half];
    __hip_bfloat16* vb = vp + (size_t)(b * 128 + t * 2) * 8192
        + (4 * h + w) * 1024 + ((l32 >> 4) & 1) * 512 + ((l32 >> 3) & 1) * 256
        + (l32 & 7);
#pragma unroll
    for (int p = 0; p < 2; p++) {
      const f32x16& O = p ? O1 : O0;
#pragma unroll
      for (int r = 0; r < 16; r++) {
        int row = (r & 3) + 8 * (r >> 2) + 4 * half;
        vb[(size_t)p * 8192 + row * 8] = __float2bfloat16(O[r] + bvv[r]);
      }
    }
  }
}

// ---------------------------------------------------------------------------
// Flash attention: K via DMA+LDS dbuf, V direct from global (frag layout).
// Block: (b, 32 queries), 4 waves = (kh, chh). 64 keys/tile, 64 tiles.
// ---------------------------------------------------------------------------
struct AttnSmem {
  union {
    __hip_bfloat16 kbuf[2][8192];   // 2 x 16 KiB
    float ostage[256][33];          // epilogue [ch][q], pad 33
  } u;
  float redu[4][32];
  float rinv[32];
};

union U4 { unsigned u[4]; bf16x8 v; };

__global__ __launch_bounds__(256, 2) void attn_kernel(
    const __hip_bfloat16* __restrict__ qv, const __hip_bfloat16* __restrict__ kv,
    const __hip_bfloat16* __restrict__ vv,
    const float* __restrict__ x_main, const float* __restrict__ gammap,
    float* __restrict__ out)
{
  __shared__ AttnSmem sm;
  const int i  = blockIdx.x;           // 512 blocks
  // XCD-stable: blockIdx%8 -> XCD; pin each XCD-pair to one batch (K+V 3MB L2-fit)
  const int b  = (i & 7) >> 1;
  const int qt = ((i >> 3) << 1) | (i & 1);   // 0..127
  const int n0 = qt * 32;
  const int tid  = threadIdx.x;
  const int w    = tid >> 6, lane = tid & 63, l32 = lane & 31, half = lane >> 5;
  const int kh   = w >> 1, chh = w & 1;

  // Q B-fragments (one-time scattered load)
  bf16x8 qf[8];
  {
    const __hip_bfloat16* qb = qv + ((size_t)(b * 4096 + n0 + l32)) * 128 + half * 8;
#pragma unroll
    for (int cs = 0; cs < 8; cs++) qf[cs] = *(const bf16x8*)(qb + cs * 16);
  }

  const __hip_bfloat16* kg = kv + (size_t)(b * 128) * 4096;
  const __hip_bfloat16* vg = vv + (size_t)(b * 128) * 8192;

  // stage one 64-key K tile: 16 chunks of 1 KiB, 4 per wave
  auto stage = [&](int t) {
    __hip_bfloat16* kd = sm.u.kbuf[t & 1];
    const __hip_bfloat16* ksrc = kg + (size_t)t * 8192 + lane * 8;
#pragma unroll
    for (int c = 0; c < 4; c++) {
      int ck = w * 4 + c;
      dma16(ksrc + ck * 512, kd + ck * 512 + lane * 8);
    }
  };

  f32x16 Oacc[4];   // 32q x 128ch (chh half), keys of kh-half
#pragma unroll
  for (int c = 0; c < 4; c++)
#pragma unroll
    for (int r = 0; r < 16; r++) Oacc[c][r] = 0.f;

  float l_lane = 0.f;

  auto qk_tile = [&](int t) -> f32x16 {
    const __hip_bfloat16* kbase = sm.u.kbuf[t & 1] + kh * 4096 + lane * 8;
    f32x16 Sa, Sb;
#pragma unroll
    for (int r = 0; r < 16; r++) { Sa[r] = 0.f; Sb[r] = 0.f; }
#pragma unroll
    for (int cs = 0; cs < 4; cs++) {
      bf16x8 kf = *(const bf16x8*)(kbase + cs * 512);
      Sa = __builtin_amdgcn_mfma_f32_32x32x16_bf16(kf, qf[cs], Sa, 0, 0, 0);
    }
#pragma unroll
    for (int cs = 4; cs < 8; cs++) {
      bf16x8 kf = *(const bf16x8*)(kbase + cs * 512);
      Sb = __builtin_amdgcn_mfma_f32_32x32x16_bf16(kf, qf[cs], Sb, 0, 0, 0);
    }
    return Sa + Sb;
  };

  // P = exp2(S - 64) (fixed rescale; softmax-invariant), in-register A-frag
  // relayout, PV from global V frag loads.
  auto pv_tile = [&](int t, const f32x16& S) {
    unsigned p2[8];
    float lsub = 0.f;
#pragma unroll
    for (int t2 = 0; t2 < 8; t2++) {
      float a = exp2f(S[2 * t2]     - 64.0f);
      float c = exp2f(S[2 * t2 + 1] - 64.0f);
      lsub += a + c;
      union { __hip_bfloat162 h; unsigned u; } cv;
      cv.h = __float22bfloat162_rn(float2{a, c});
      p2[t2] = cv.u;
    }
    l_lane += lsub;
    unsigned r2[8];
#pragma unroll
    for (int t2 = 0; t2 < 8; t2++) r2[t2] = (unsigned)__shfl_xor((int)p2[t2], 32);
    U4 f0, f1;
    if (half == 0) {
      f0.u[0] = p2[0]; f0.u[1] = p2[1]; f0.u[2] = r2[0]; f0.u[3] = r2[1];
      f1.u[0] = p2[4]; f1.u[1] = p2[5]; f1.u[2] = r2[4]; f1.u[3] = r2[5];
    } else {
      f0.u[0] = r2[2]; f0.u[1] = r2[3]; f0.u[2] = p2[2]; f0.u[3] = p2[3];
      f1.u[0] = r2[6]; f1.u[1] = r2[7]; f1.u[2] = p2[6]; f1.u[3] = p2[7];
    }
    const bf16x8 pf0 = f0.v, pf1 = f1.v;
    const __hip_bfloat16* vb = vg + (size_t)(t * 2 + kh) * 8192
                             + chh * 4096 + lane * 8;
#pragma unroll
    for (int c = 0; c < 4; c++) {
      bf16x8 v0 = *(const bf16x8*)(vb + c * 1024);
      Oacc[c] = __builtin_amdgcn_mfma_f32_32x32x16_bf16(pf0, v0, Oacc[c], 0, 0, 0);
      bf16x8 v1 = *(const bf16x8*)(vb + c * 1024 + 512);
      Oacc[c] = __builtin_amdgcn_mfma_f32_32x32x16_bf16(pf1, v1, Oacc[c], 0, 0, 0);
    }
  };

  // ---- pipelined main loop, 1 barrier/tile ----
  stage(0);
  __syncthreads();                 // tile 0 landed
  stage(1);
  {
    f32x16 S = qk_tile(0);
    pv_tile(0, S);
  }
#pragma unroll 1
  for (int t = 1; t < 64; ++t) {
    __syncthreads();               // drains stage(t); separates buf reuse
    if (t < 63) stage(t + 1);
    f32x16 S = qk_tile(t);
    pv_tile(t, S);
  }

  // ---- epilogue: publish l, kh-merge via ostage, fused writeout ----
  float lfull = l_lane + __shfl_xor(l_lane, 32);
  if (lane < 32) sm.redu[w][l32] = lfull;
  __syncthreads();                 // E1: kbuf reads done; redu published
  if (kh == 0) {
#pragma unroll
    for (int c = 0; c < 4; c++) {
      int ch = (chh * 4 + c) * 32 + l32;
#pragma unroll
      for (int r = 0; r < 16; r++) {
        int q = (r & 3) + 8 * (r >> 2) + 4 * half;
        sm.u.ostage[ch][q] = Oacc[c][r];
      }
    }
  }
  if (tid < 32) sm.rinv[tid] = 1.0f / (sm.redu[0][tid] + sm.redu[2][tid]);
  __syncthreads();                 // E2
  if (kh == 1) {
#pragma unroll
    for (int c = 0; c < 4; c++) {
      int ch = (chh * 4 + c) * 32 + l32;
#pragma unroll
      for (int r = 0; r < 16; r++) {
        int q = (r & 3) + 8 * (r >> 2) + 4 * half;
        sm.u.ostage[ch][q] += Oacc[c][r];
      }
    }
  }
  __syncthreads();                 // E3

  const float gmm = gammap[0];
  const int pix = tid & 31;
  const float ri = sm.rinv[pix];
#pragma unroll
  for (int j = 0; j < 32; ++j) {
    int ch = (tid >> 5) * 32 + j;
    size_t g = ((size_t)(b * 256 + ch)) * 4096 + n0 + pix;
    out[g] = gmm * sm.u.ostage[ch][pix] * ri + x_main[g];
  }
}

// ---------------------------------------------------------------------------
extern "C" void kernel_launch(void* const* d_in, const int* in_sizes, int n_in,
                              void* d_out, int out_size, void* d_ws, size_t ws_size,
                              hipStream_t stream) {
  (void)in_sizes; (void)n_in; (void)out_size; (void)ws_size;
  const float* x  = (const float*)d_in[0];
  const float* z  = (const float*)d_in[1];
  const float* Wq = (const float*)d_in[2];
  const float* bq = (const float*)d_in[3];
  const float* Wk = (const float*)d_in[4];
  const float* bk = (const float*)d_in[5];
  const float* Wv = (const float*)d_in[6];
  const float* bv = (const float*)d_in[7];
  const float* gm = (const float*)d_in[8];
  float* out = (float*)d_out;

  char* ws = (char*)d_ws;
  const size_t QSZ = (size_t)4 * 4096 * 128 * sizeof(__hip_bfloat16);  // 4 MiB
  __hip_bfloat16* qp = (__hip_bfloat16*)(ws);
  __hip_bfloat16* kp = (__hip_bfloat16*)(ws + QSZ);
  __hip_bfloat16* vp = (__hip_bfloat16*)(ws + 2 * QSZ);                // 8 MiB

  const int proj_smem = 256 * 64 * sizeof(float);   // 64 KiB dynamic
  (void)hipFuncSetAttribute((const void*)proj_mfma,
                            hipFuncAttributeMaxDynamicSharedMemorySize,
                            proj_smem);

  proj_mfma<<<1024, 256, proj_smem, stream>>>(x, z, Wq, bq, Wk, bk, Wv, bv,
                                              qp, kp, vp);
  attn_kernel<<<512, 256, 0, stream>>>(qp, kp, vp, x, gm, out);
}

// Round 6
// 215.388 us; speedup vs baseline: 1.8704x; 1.1244x over previous
//
#include <hip/hip_runtime.h>
#include <hip/hip_bf16.h>

// CrossAttentionFusion: B=4, C=Cs=256, CI=128, H=W=64 -> N=M=4096
// R6:
//  - prep: convert W and x/z to bf16 MFMA-fragment-order buffers (one pass).
//  - proj: LDS-free MFMA GEMM; W frags in VGPRs, X frags coalesced b128 from
//    global (L1-cached across waves); stores q/K/V in attn-consumable layouts.
//  - attn: key-permutation trick makes P exit QK^T already in PV B-operand
//    register order (K-frag rows permuted m<->m^12 for (m>>2)&3 in {1,2});
//    zero cross-lane shuffles. PV: A=V, B=P -> O^T (ch rows). 3 blocks/CU.
//
// qk-frag (Q B-op / K A-op), per 32-row group g of rows r (r=query or key):
//   addr = g*4096 + (ch>>4)*512 + ((ch>>3)&1)*256 + row*8 + (ch&7)
//   (K uses row = perm(key&31); Q uses row = n&31 unpermuted)
// V-frag (PV A-op), per 32-key group: addr = g*8192 + (ch>>5)*1024
//   + ((key>>4)&1)*512 + ((key>>3)&1)*256 + (ch&31)*8 + (key&7)
// X-frag (proj B-op), per 32-pix group: addr = g*8192 + (cs)*512
//   + ((ch>>3)&1)*256 + (pix&31)*8 + (ch&7)   [cs = ch>>4, 256 in-ch]
// W-frag (proj A-op), per 32-och tile: addr = tile*8192 + cs*512
//   + ((ch>>3)&1)*256 + (och&31)*8 + (ch&7)

typedef __bf16  bf16x8  __attribute__((ext_vector_type(8)));
typedef float   f32x16  __attribute__((ext_vector_type(16)));

#define LOG2E 1.4426950408889634f

union BF8 { __hip_bfloat162 h[4]; bf16x8 v; };
union U4  { unsigned u[4]; bf16x8 v; };

__device__ inline bf16x8 pack8(const float f[8]) {
  BF8 u;
#pragma unroll
  for (int i = 0; i < 4; i++)
    u.h[i] = __float22bfloat162_rn(float2{f[2 * i], f[2 * i + 1]});
  return u.v;
}

__device__ inline void dma16(const void* g, void* l) {
  __builtin_amdgcn_global_load_lds(
      (const __attribute__((address_space(1))) unsigned int*)g,
      (__attribute__((address_space(3))) unsigned int*)l, 16, 0, 0);
}

// ---------------------------------------------------------------------------
// prep: blocks [0,512): x/z -> X-frag bf16 (LDS transpose);
//       blocks [512,516): W -> W-frag bf16.
// ---------------------------------------------------------------------------
__global__ __launch_bounds__(256) void prep_kernel(
    const float* __restrict__ x, const float* __restrict__ z,
    const float* __restrict__ Wq, const float* __restrict__ Wk,
    const float* __restrict__ Wv,
    __hip_bfloat16* __restrict__ xf, __hip_bfloat16* __restrict__ zf,
    __hip_bfloat16* __restrict__ wfr)
{
  __shared__ float lds[256 * 65];
  const int bi = blockIdx.x;
  const int tid = threadIdx.x;
  if (bi < 512) {
    const int sel = bi >> 8;          // 0: x, 1: z
    const int b   = (bi >> 6) & 3;
    const int pc  = bi & 63;          // 64-pixel tile
    const float* in = sel ? z : x;
    __hip_bfloat16* outp = sel ? zf : xf;
    const size_t ib = (size_t)b * 256 * 4096 + pc * 64;
#pragma unroll 4
    for (int r = 0; r < 64; r++) {
      int ch = r * 4 + (tid >> 6);
      lds[ch * 65 + (tid & 63)] = in[ib + (size_t)ch * 4096 + (tid & 63)];
    }
    __syncthreads();
    const size_t ob = ((size_t)(b * 128 + pc * 2)) * 8192;
#pragma unroll
    for (int i = 0; i < 8; i++) {
      int c = i * 256 + tid;                    // 2048 16B-chunks
      int grp = c >> 10, cs = (c >> 6) & 15, rem = c & 63;
      int hf = rem >> 5, l32 = rem & 31;
      float f[8];
      int chb = cs * 16 + hf * 8;
#pragma unroll
      for (int j = 0; j < 8; j++)
        f[j] = lds[(chb + j) * 65 + grp * 32 + l32];
      *(bf16x8*)(outp + ob + grp * 8192 + cs * 512 + hf * 256 + l32 * 8) =
          pack8(f);
    }
  } else {
    const int base = (bi - 512) * 4096;
#pragma unroll
    for (int i = 0; i < 16; i++) {
      int c = base + i * 256 + tid;             // [0, 16384)
      const float* Ws; __hip_bfloat16* dst; int rc;
      if (c < 4096)      { Ws = Wq; dst = wfr;          rc = c; }
      else if (c < 8192) { Ws = Wk; dst = wfr + 32768;  rc = c - 4096; }
      else               { Ws = Wv; dst = wfr + 65536;  rc = c - 8192; }
      int ot = rc >> 10, cs = (rc >> 6) & 15, rem = rc & 63;
      int hf = rem >> 5, l32 = rem & 31;
      const float* src = Ws + (ot * 32 + l32) * 256 + cs * 16 + hf * 8;
      float f[8];
#pragma unroll
      for (int j = 0; j < 8; j++) f[j] = src[j];
      *(bf16x8*)(dst + ot * 8192 + cs * 512 + hf * 256 + l32 * 8) = pack8(f);
    }
  }
}

// ---------------------------------------------------------------------------
// proj: LDS-free MFMA GEMM. Grid 512: [0,128) q, [128,256) k, [256,512) v.
// Block: (b, 128-pixel chunk); wave = 32-och tile; 4 iters of 32 pixels.
// ---------------------------------------------------------------------------
__global__ __launch_bounds__(256, 2) void proj_mfma(
    const __hip_bfloat16* __restrict__ xf, const __hip_bfloat16* __restrict__ zf,
    const __hip_bfloat16* __restrict__ wfr,
    const float* __restrict__ bq, const float* __restrict__ bk,
    const float* __restrict__ bv,
    __hip_bfloat16* __restrict__ qp, __hip_bfloat16* __restrict__ kp,
    __hip_bfloat16* __restrict__ vp)
{
  const int bi = blockIdx.x;
  int mode, b, pc, h = 0;
  if (bi < 256) { mode = bi >> 7; b = (bi >> 5) & 3; pc = bi & 31; }
  else { int j = bi - 256; mode = 2; b = j >> 6; pc = (j >> 1) & 31; h = j & 1; }
  const int tid = threadIdx.x, w = tid >> 6, lane = tid & 63,
            l32 = lane & 31, half = lane >> 5;

  const __hip_bfloat16* X = (mode == 0) ? xf : zf;
  const int wtile = (mode == 2 ? h * 4 : 0) + w;
  const int wbase = (mode == 0) ? 0 : (mode == 1) ? 32768 : 65536;
  const __hip_bfloat16* wp = wfr + wbase + wtile * 8192 + lane * 8;
  bf16x8 wfg[16];
#pragma unroll
  for (int cs = 0; cs < 16; cs++) wfg[cs] = *(const bf16x8*)(wp + cs * 512);

  const float* bias = (mode == 0) ? bq : (mode == 1) ? bk : bv;
  const int ochb = (mode == 2 ? h * 128 : 0) + w * 32;
  float bb[16];
#pragma unroll
  for (int r = 0; r < 16; r++)
    bb[r] = bias[ochb + (r & 3) + 8 * (r >> 2) + 4 * half];

  // key permutation for K A-operand rows (shuffle-free PV in attn)
  const int t4 = (l32 >> 2) & 3;
  const int kperm = (t4 == 1 || t4 == 2) ? (l32 ^ 12) : l32;

#pragma unroll 1
  for (int it = 0; it < 4; it++) {
    const int pg = pc * 4 + it;                 // 32-pix group
    const __hip_bfloat16* xb = X + ((size_t)(b * 128 + pg)) * 8192 + lane * 8;
    f32x16 O = {};
#pragma unroll
    for (int cs = 0; cs < 16; cs++) {
      bf16x8 xr = *(const bf16x8*)(xb + cs * 512);
      O = __builtin_amdgcn_mfma_f32_32x32x16_bf16(wfg[cs], xr, O, 0, 0, 0);
    }
    if (mode == 0) {
      __hip_bfloat16* qb = qp + ((size_t)(b * 128 + pg)) * 4096;
#pragma unroll
      for (int r = 0; r < 16; r++) {
        int oc = ochb + (r & 3) + 8 * (r >> 2) + 4 * half;
        qb[(oc >> 4) * 512 + ((oc >> 3) & 1) * 256 + l32 * 8 + (oc & 7)] =
            __float2bfloat16((O[r] + bb[r]) * LOG2E);
      }
    } else if (mode == 1) {
      __hip_bfloat16* kb = kp + ((size_t)(b * 128 + pg)) * 4096;
#pragma unroll
      for (int r = 0; r < 16; r++) {
        int oc = ochb + (r & 3) + 8 * (r >> 2) + 4 * half;
        kb[(oc >> 4) * 512 + ((oc >> 3) & 1) * 256 + kperm * 8 + (oc & 7)] =
            __float2bfloat16(O[r] + bb[r]);
      }
    } else {
      __hip_bfloat16* vb = vp + ((size_t)(b * 128 + pg)) * 8192
          + (h * 4 + w) * 1024 + (l32 >> 4) * 512 + ((l32 >> 3) & 1) * 256
          + (l32 & 7);
#pragma unroll
      for (int r = 0; r < 16; r++) {
        int rr = (r & 3) + 8 * (r >> 2) + 4 * half;
        vb[rr * 8] = __float2bfloat16(O[r] + bb[r]);
      }
    }
  }
}

// ---------------------------------------------------------------------------
// attn: shuffle-free flash attention. Block (b, 32 q), 4 waves = (kh,chh).
// 64 keys/tile via K DMA+LDS dbuf; V direct global frag loads; 64 tiles.
// ---------------------------------------------------------------------------
struct AttnSmem {
  union {
    __hip_bfloat16 kbuf[2][8192];   // 2 x 16 KiB
    float ostage[256][33];          // epilogue [ch][q], pad 33
  } u;
  float redu[4][32];
  float rinv[32];
};

__global__ __launch_bounds__(256, 3) void attn_kernel(
    const __hip_bfloat16* __restrict__ qv, const __hip_bfloat16* __restrict__ kv,
    const __hip_bfloat16* __restrict__ vv,
    const float* __restrict__ x_main, const float* __restrict__ gammap,
    float* __restrict__ out)
{
  __shared__ AttnSmem sm;
  const int i  = blockIdx.x;           // 512 blocks
  const int b  = (i & 7) >> 1;         // XCD-pair -> batch (K+V L2-resident)
  const int qt = ((i >> 3) << 1) | (i & 1);
  const int n0 = qt * 32;
  const int tid  = threadIdx.x;
  const int w    = tid >> 6, lane = tid & 63, l32 = lane & 31;
  const int kh   = w >> 1, chh = w & 1;

  // Q B-fragments: coalesced frag-order load
  bf16x8 qf[8];
  {
    const __hip_bfloat16* qb = qv + ((size_t)(b * 128 + qt)) * 4096 + lane * 8;
#pragma unroll
    for (int cs = 0; cs < 8; cs++) qf[cs] = *(const bf16x8*)(qb + cs * 512);
  }

  const __hip_bfloat16* kg = kv + (size_t)(b * 128) * 4096;
  const __hip_bfloat16* vg = vv + (size_t)(b * 128) * 8192;

  auto stage = [&](int t) {
    __hip_bfloat16* kd = sm.u.kbuf[t & 1];
    const __hip_bfloat16* ksrc = kg + (size_t)t * 8192 + lane * 8;
#pragma unroll
    for (int c = 0; c < 4; c++) {
      int ck = w * 4 + c;
      dma16(ksrc + ck * 512, kd + ck * 512 + lane * 8);
    }
  };

  f32x16 Oacc[4];   // O^T: 128 ch (chh half) x 32 q, keys of kh-half
#pragma unroll
  for (int c = 0; c < 4; c++)
#pragma unroll
    for (int r = 0; r < 16; r++) Oacc[c][r] = 0.f;

  float l_lane = 0.f;

  auto qk_tile = [&](int t) -> f32x16 {
    const __hip_bfloat16* kbase = sm.u.kbuf[t & 1] + kh * 4096 + lane * 8;
    f32x16 S = {};
#pragma unroll
    for (int cs = 0; cs < 8; cs++) {
      bf16x8 kf = *(const bf16x8*)(kbase + cs * 512);
      S = __builtin_amdgcn_mfma_f32_32x32x16_bf16(kf, qf[cs], S, 0, 0, 0);
    }
    return S;
  };

  // P = exp2(S-64). Key permutation at K-write time means p2[0..3]/p2[4..7]
  // ARE the PV B-operand fragments: no cross-lane movement.
  auto pv_tile = [&](int t, const f32x16& S) {
    unsigned p2[8];
    float s0 = 0.f, s1 = 0.f;
#pragma unroll
    for (int i2 = 0; i2 < 8; i2++) {
      float a = exp2f(S[2 * i2]     - 64.0f);
      float c = exp2f(S[2 * i2 + 1] - 64.0f);
      if (i2 & 1) s1 += a + c; else s0 += a + c;
      union { __hip_bfloat162 h; unsigned u; } cv;
      cv.h = __float22bfloat162_rn(float2{a, c});
      p2[i2] = cv.u;
    }
    l_lane += s0 + s1;
    U4 f0, f1;
    f0.u[0] = p2[0]; f0.u[1] = p2[1]; f0.u[2] = p2[2]; f0.u[3] = p2[3];
    f1.u[0] = p2[4]; f1.u[1] = p2[5]; f1.u[2] = p2[6]; f1.u[3] = p2[7];
    const bf16x8 pf0 = f0.v, pf1 = f1.v;
    const __hip_bfloat16* vb = vg + (size_t)(t * 2 + kh) * 8192
                             + chh * 4096 + lane * 8;
#pragma unroll
    for (int c = 0; c < 4; c++) {
      bf16x8 v0 = *(const bf16x8*)(vb + c * 1024);
      Oacc[c] = __builtin_amdgcn_mfma_f32_32x32x16_bf16(v0, pf0, Oacc[c], 0, 0, 0);
      bf16x8 v1 = *(const bf16x8*)(vb + c * 1024 + 512);
      Oacc[c] = __builtin_amdgcn_mfma_f32_32x32x16_bf16(v1, pf1, Oacc[c], 0, 0, 0);
    }
  };

  // ---- pipelined main loop, 1 barrier/tile ----
  stage(0);
  __syncthreads();                 // tile 0 landed
  stage(1);
  {
    f32x16 S = qk_tile(0);
    pv_tile(0, S);
  }
#pragma unroll 1
  for (int t = 1; t < 64; ++t) {
    __syncthreads();               // drains stage(t); separates buf reuse
    if (t < 63) stage(t + 1);
    f32x16 S = qk_tile(t);
    pv_tile(t, S);
  }

  // ---- epilogue: publish l, kh-merge via ostage (ch rows), writeout ----
  float lfull = l_lane + __shfl_xor(l_lane, 32);
  if (lane < 32) sm.redu[w][l32] = lfull;
  __syncthreads();                 // kbuf reads done; redu published
  const int hb = lane >> 5;
  if (kh == 0) {
#pragma unroll
    for (int c = 0; c < 4; c++) {
#pragma unroll
      for (int r = 0; r < 16; r++) {
        int ch = (chh * 4 + c) * 32 + (r & 3) + 8 * (r >> 2) + 4 * hb;
        sm.u.ostage[ch][l32] = Oacc[c][r];
      }
    }
  }
  if (tid < 32) sm.rinv[tid] = 1.0f / (sm.redu[0][tid] + sm.redu[2][tid]);
  __syncthreads();
  if (kh == 1) {
#pragma unroll
    for (int c = 0; c < 4; c++) {
#pragma unroll
      for (int r = 0; r < 16; r++) {
        int ch = (chh * 4 + c) * 32 + (r & 3) + 8 * (r >> 2) + 4 * hb;
        sm.u.ostage[ch][l32] += Oacc[c][r];
      }
    }
  }
  __syncthreads();

  const float gmm = gammap[0];
  const int pix = tid & 31;
  const float ri = sm.rinv[pix];
#pragma unroll
  for (int j = 0; j < 32; ++j) {
    int ch = (tid >> 5) * 32 + j;
    size_t g = ((size_t)(b * 256 + ch)) * 4096 + n0 + pix;
    out[g] = gmm * sm.u.ostage[ch][pix] * ri + x_main[g];
  }
}

// ---------------------------------------------------------------------------
extern "C" void kernel_launch(void* const* d_in, const int* in_sizes, int n_in,
                              void* d_out, int out_size, void* d_ws, size_t ws_size,
                              hipStream_t stream) {
  (void)in_sizes; (void)n_in; (void)out_size; (void)ws_size;
  const float* x  = (const float*)d_in[0];
  const float* z  = (const float*)d_in[1];
  const float* Wq = (const float*)d_in[2];
  const float* bq = (const float*)d_in[3];
  const float* Wk = (const float*)d_in[4];
  const float* bk = (const float*)d_in[5];
  const float* Wv = (const float*)d_in[6];
  const float* bv = (const float*)d_in[7];
  const float* gm = (const float*)d_in[8];
  float* out = (float*)d_out;

  char* ws = (char*)d_ws;
  const size_t MB = 1024 * 1024;
  __hip_bfloat16* qp  = (__hip_bfloat16*)(ws);             // 4 MiB
  __hip_bfloat16* kp  = (__hip_bfloat16*)(ws + 4 * MB);    // 4 MiB
  __hip_bfloat16* vp  = (__hip_bfloat16*)(ws + 8 * MB);    // 8 MiB
  __hip_bfloat16* xfp = (__hip_bfloat16*)(ws + 16 * MB);   // 8 MiB
  __hip_bfloat16* zfp = (__hip_bfloat16*)(ws + 24 * MB);   // 8 MiB
  __hip_bfloat16* wfp = (__hip_bfloat16*)(ws + 32 * MB);   // 256 KiB

  prep_kernel<<<516, 256, 0, stream>>>(x, z, Wq, Wk, Wv, xfp, zfp, wfp);
  proj_mfma  <<<512, 256, 0, stream>>>(xfp, zfp, wfp, bq, bk, bv, qp, kp, vp);
  attn_kernel<<<512, 256, 0, stream>>>(qp, kp, vp, x, gm, out);
}